// Round 5
// baseline (559.276 us; speedup 1.0000x reference)
//
#include <hip/hip_runtime.h>
#include <math.h>

// AxileAttention: out = softmax((X@Wq+bq)*(X@Wk+bk), -1) * (X@Wv+bv), per (b,c).
// B=8 C=64 H=256 W=256, fp32 in/out.
//
// Round 12: fused + restored W-reuse + counted-vmcnt 3-buffer pipeline.
// R11 post-mortem: fusing at M=32 halved W-reuse (2.6GB LDS-fill) and the
// __syncthreads vmcnt(0) drain exposed full latency every kt -> 356us.
// Fix: M=64 blocks (grid 2048, W-reuse back to R10 level), 1024 threads =
// 16 waves of 32x32 tiles (acc stays 48 f32, VGPR ~112), and T3/T4: 3 LDS
// buffers, stage tile kt+2 during compute of kt, raw s_barrier with
// asm s_waitcnt vmcnt(N) (N = kt+2's in-flight stage instrs) so W loads
// fly ACROSS barriers; ~500cyc shadow per load. LDS 3x40KB=120KB ->
// 1 block/CU, 16 waves. Epilogue aliases buf0 after final barrier.
// prep_w (W->f16 hi/lo fragment planes in d_ws) unchanged; R8 fallback kept.

#define Bn 8
#define Cn 64
#define Hn 256
#define Wn 256

typedef _Float16 f16x8 __attribute__((ext_vector_type(8)));
typedef _Float16 f16x4 __attribute__((ext_vector_type(4)));
typedef float    f32x16 __attribute__((ext_vector_type(16)));

#define MFMA(a, b, c) __builtin_amdgcn_mfma_f32_32x32x16_f16((a), (b), (c), 0, 0, 0)

// ws layout: plane(c,kt,p) = ((c*16+kt)*5+p) * 8192 bytes, p: 0=qh 1=ql 2=kh 3=kl 4=vh
// within plane: ntile*1024 + (khalf*32+nl)*16 bytes = f16x8 of rows k0+khalf*8..+8 at col n
// Planes of one kt are contiguous: one 40960B tile per (c,kt).
#define WS_PLANE_H 4096   // _Float16 elements per plane (8192 B)
#define WS_NEED ((size_t)Cn * 16 * 5 * 8192)

#define FTILE 40960       // 5 planes * 8192 B

__device__ __forceinline__ void ldst16(const void* g, void* l) {
    __builtin_amdgcn_global_load_lds(
        (const __attribute__((address_space(1))) unsigned int*)g,
        (__attribute__((address_space(3))) unsigned int*)l, 16, 0, 0);
}

__device__ __forceinline__ void cvt_hilo(const float4 a, const float4 b,
                                         f16x8& hi, f16x8& lo) {
    float v[8] = {a.x, a.y, a.z, a.w, b.x, b.y, b.z, b.w};
#pragma unroll
    for (int e = 0; e < 8; ++e) {
        _Float16 hv = (_Float16)v[e];
        hi[e] = hv;
        lo[e] = (_Float16)(v[e] - (float)hv);
    }
}

// ---------------- prep: W (f32) -> fragment-ordered f16 hi/lo planes ----------------
__global__ __launch_bounds__(256) void prep_w(
    const float* __restrict__ wq, const float* __restrict__ wk,
    const float* __restrict__ wv, _Float16* __restrict__ wf)
{
    const int blk = blockIdx.x;          // c*16 + kt
    const int kt  = blk & 15;
    const int c   = blk >> 4;
    const int n   = threadIdx.x;         // column 0..255
    const int ntile = n >> 5;
    const int nl    = n & 31;

    _Float16* base = wf + (size_t)blk * 5 * WS_PLANE_H;
    const size_t woff = ((size_t)c * Wn + kt * 16) * Wn + n;

#pragma unroll
    for (int mat = 0; mat < 2; ++mat) {      // 0=q, 1=k : hi+lo planes
        const float* Wp = (mat ? wk : wq) + woff;
        float w16[16];
#pragma unroll
        for (int r = 0; r < 16; ++r)
            w16[r] = Wp[(size_t)r * Wn];
        _Float16* hip = base + (mat * 2) * WS_PLANE_H + ntile * 512;
        _Float16* lop = hip + WS_PLANE_H;
#pragma unroll
        for (int h2 = 0; h2 < 2; ++h2) {
            f16x8 hi8, lo8;
#pragma unroll
            for (int e = 0; e < 8; ++e) {
                const float wv_ = w16[h2 * 8 + e];
                _Float16 hv = (_Float16)wv_;
                hi8[e] = hv;
                lo8[e] = (_Float16)(wv_ - (float)hv);
            }
            *(f16x8*)(hip + (h2 * 32 + nl) * 8) = hi8;
            *(f16x8*)(lop + (h2 * 32 + nl) * 8) = lo8;
        }
    }
    {   // v: hi only (plane 4)
        const float* Wp = wv + woff;
        float w16[16];
#pragma unroll
        for (int r = 0; r < 16; ++r)
            w16[r] = Wp[(size_t)r * Wn];
        _Float16* vp = base + 4 * WS_PLANE_H + ntile * 512;
#pragma unroll
        for (int h2 = 0; h2 < 2; ++h2) {
            f16x8 hi8;
#pragma unroll
            for (int e = 0; e < 8; ++e)
                hi8[e] = (_Float16)w16[h2 * 8 + e];
            *(f16x8*)(vp + (h2 * 32 + nl) * 8) = hi8;
        }
    }
}

// ---------------- main: fused, M=64, 16 waves, 3-buf counted-vmcnt ----------------
__global__ __launch_bounds__(1024, 4) void axile_attn_pipe(
    const float* __restrict__ x,
    const _Float16* __restrict__ wf,
    const float* __restrict__ bq,
    const float* __restrict__ bk,
    const float* __restrict__ bv,
    float* __restrict__ out)
{
    __shared__ __align__(16) char lds[3 * FTILE];   // 120 KB -> 1 block/CU

    const int tid   = threadIdx.x;
    const int lane  = tid & 63;
    const int h     = lane >> 5;
    const int l31   = lane & 31;
    const int wv_id = tid >> 6;        // 0..15
    const int ncol  = wv_id & 7;       // 32-col strip
    const int mt    = wv_id >> 3;      // 32-row half of the 64-row tile

    // blk = (ht*8 + b)*64 + c : c low bits -> XCD affinity per channel.
    const int blk = blockIdx.x;
    const int c   = blk & 63;
    const int j   = blk >> 6;          // ht*8 + b, ht 0..3
    const int b   = j & 7;
    const int h0  = (j >> 3) * 64;

    const float* xrow = x + ((size_t)(b * Cn + c) * Hn + h0 + mt * 32 + l31) * Wn + h * 8;
    const char*  wfc  = (const char*)(wf + (size_t)c * 16 * 5 * WS_PLANE_H);

    // W staging: 40960 B per tile, 1024 thr x 16 B = 16 KB per round;
    // rounds 0,1 full + round 2 for tid<512 (wave-uniform predicate).
    const bool halfw = (tid < 512);
    const int  so0 = tid * 16;
    const int  so1 = 16384 + tid * 16;
    const int  so2 = 32768 + tid * 16;

    f32x16 accq, acck, accv;
#pragma unroll
    for (int r = 0; r < 16; ++r) {
        accq[r] = 0.f;
        acck[r] = 0.f;
        accv[r] = 0.f;
    }

    // ---- prologue: x(0) regs; W(0)->buf0, W(1)->buf1 ----
    f16x8 ah, al;
    {
        const float4 xa = *(const float4*)(xrow);
        const float4 xb = *(const float4*)(xrow + 4);
        ldst16(wfc + so0, lds + so0);
        ldst16(wfc + so1, lds + so1);
        if (halfw) ldst16(wfc + so2, lds + so2);
        const char* s1 = wfc + FTILE;
        ldst16(s1 + so0, lds + FTILE + so0);
        ldst16(s1 + so1, lds + FTILE + so1);
        if (halfw) ldst16(s1 + so2, lds + FTILE + so2);
        cvt_hilo(xa, xb, ah, al);      // compiler waits the x regs
    }
    // W(0) done, W(1) (newest 2-3) may fly:
    if (halfw) asm volatile("s_waitcnt vmcnt(3)" ::: "memory");
    else       asm volatile("s_waitcnt vmcnt(2)" ::: "memory");
    __builtin_amdgcn_s_barrier();
    __builtin_amdgcn_sched_barrier(0);

    // ================= fused K-loop: 16 iters, 7 MFMA, 1 raw barrier =================
    int o_cur = 0, o_nxt = FTILE, o_sta = 2 * FTILE;
    for (int kt = 0; kt < 16; ++kt) {
        float4 ya, yb;
        if (kt < 15) {                 // x for kt+1 (oldest VMEM this iter)
            ya = *(const float4*)(xrow + (kt + 1) * 16);
            yb = *(const float4*)(xrow + (kt + 1) * 16 + 4);
        }
        if (kt < 14) {                 // W tile kt+2 -> o_sta (stays in flight)
            const char* ssrc = wfc + (size_t)(kt + 2) * FTILE;
            ldst16(ssrc + so0, lds + o_sta + so0);
            ldst16(ssrc + so1, lds + o_sta + so1);
            if (halfw) ldst16(ssrc + so2, lds + o_sta + so2);
        }

        const char* bb = lds + o_cur + ncol * 1024 + lane * 16;
        const f16x8 bqh = *(const f16x8*)(bb);
        const f16x8 bql = *(const f16x8*)(bb + 8192);
        const f16x8 bkh = *(const f16x8*)(bb + 16384);
        const f16x8 bkl = *(const f16x8*)(bb + 24576);
        const f16x8 bvh = *(const f16x8*)(bb + 32768);

        accq = MFMA(ah, bqh, accq);
        accq = MFMA(al, bqh, accq);
        accq = MFMA(ah, bql, accq);
        acck = MFMA(ah, bkh, acck);
        acck = MFMA(al, bkh, acck);
        acck = MFMA(ah, bkl, acck);
        accv = MFMA(ah, bvh, accv);

        if (kt < 15)
            cvt_hilo(ya, yb, ah, al);  // next-iter A frags (hides x latency)

        if (kt < 14) {
            // wait W(kt+1)+x done; W(kt+2)'s 2-3 stay in flight across barrier
            if (halfw) asm volatile("s_waitcnt vmcnt(3)" ::: "memory");
            else       asm volatile("s_waitcnt vmcnt(2)" ::: "memory");
        } else if (kt == 14) {
            asm volatile("s_waitcnt vmcnt(0)" ::: "memory");   // drain W(15)+x(15)
        }
        __builtin_amdgcn_s_barrier();
        __builtin_amdgcn_sched_barrier(0);
        const int t = o_cur; o_cur = o_nxt; o_nxt = o_sta; o_sta = t;
    }

    // ---- softmax scratch aliases buf0 (safe: all LDS reads retired at final barrier) ----
    float* part    = (float*)lds;            // [8 nstrips][64 rows]
    float* combmax = (float*)(lds + 2048);   // [64]
    float* combsum = (float*)(lds + 2304);   // [64]

    // ---- s = (q+bq)*(k+bk) into accq ----
#pragma unroll
    for (int r = 0; r < 16; ++r) {
        const int row = mt * 32 + (r & 3) + 8 * (r >> 2) + 4 * h;
        const int vv  = ncol * 32 + l31;
        const size_t bidx = ((size_t)c * Hn + h0 + row) * Wn + vv;
        const float qv = accq[r] + bq[bidx];
        const float kv = acck[r] + bk[bidx];
        accq[r] = qv * kv;
    }

    // ---- row max (reduce over l31; h halves separate) ----
#pragma unroll
    for (int r = 0; r < 16; ++r) {
        float m2 = accq[r];
#pragma unroll
        for (int off = 16; off > 0; off >>= 1)
            m2 = fmaxf(m2, __shfl_xor(m2, off, 64));
        if ((lane & 31) == r) {
            const int row = mt * 32 + (r & 3) + 8 * (r >> 2) + 4 * h;
            part[ncol * 64 + row] = m2;
        }
    }
    __syncthreads();
    if (tid < 64) {
        float m = part[tid];
#pragma unroll
        for (int w = 1; w < 8; ++w)
            m = fmaxf(m, part[w * 64 + tid]);
        combmax[tid] = m;
    }
    __syncthreads();

    // ---- e = exp(s - mx); row sum ----
#pragma unroll
    for (int r = 0; r < 16; ++r) {
        const int row = mt * 32 + (r & 3) + 8 * (r >> 2) + 4 * h;
        const float mx = combmax[row];
        const float e0 = __expf(accq[r] - mx);
        accq[r] = e0;
        float ps = e0;
#pragma unroll
        for (int off = 16; off > 0; off >>= 1)
            ps += __shfl_xor(ps, off, 64);
        if ((lane & 31) == r)
            part[ncol * 64 + row] = ps;
    }
    __syncthreads();
    if (tid < 64) {
        float s = part[tid];
#pragma unroll
        for (int w = 1; w < 8; ++w)
            s += part[w * 64 + tid];
        combsum[tid] = s;
    }
    __syncthreads();

    // ---- out = e * (v + bv) / sum ----
    float* obase = out + ((size_t)(b * Cn + c) * Hn) * Wn;
#pragma unroll
    for (int r = 0; r < 16; ++r) {
        const int row = mt * 32 + (r & 3) + 8 * (r >> 2) + 4 * h;
        const float inv = 1.0f / combsum[row];
        const int hh = h0 + row;
        const int vv = ncol * 32 + l31;
        const size_t bidx = ((size_t)c * Hn + hh) * Wn + vv;
        const float vx = accv[r] + bv[bidx];
        obase[(size_t)hh * Wn + vv] = accq[r] * vx * inv;
    }
}

// ---------------- fallback (R8): in-kernel W conversion, no ws ----------------
#define LDS_ALO 2048
#define LDS_B   4096

__global__ __launch_bounds__(512, 4) void axile_attn_mfma4(
    const float* __restrict__ x,
    const float* __restrict__ wq,
    const float* __restrict__ wk,
    const float* __restrict__ wv,
    const float* __restrict__ bq,
    const float* __restrict__ bk,
    const float* __restrict__ bv,
    float* __restrict__ out)
{
    __shared__ __align__(16) char lds[39424];

    const int tid  = threadIdx.x;
    const int ncol = tid >> 6;
    const int lane = tid & 63;
    const int h    = lane >> 5;
    const int l31  = lane & 31;

    const int blk = blockIdx.x;
    const int c   = blk & 63;
    const int j   = blk >> 6;
    const int b   = j & 7;
    const int h0  = (j >> 3) * 64;

    const float* xbase = x + ((size_t)(b * Cn + c) * Hn + h0) * Wn;
    const float* w_q = wq + (size_t)c * Wn * Wn;
    const float* w_k = wk + (size_t)c * Wn * Wn;
    const float* w_v = wv + (size_t)c * Wn * Wn;

    const int wkh = tid >> 8;
    const int n   = tid & 255;
    const int ntW = n >> 5;
    const int nl  = n & 31;
    const int wfo = ((wkh << 5) | nl) * 16;
    const int am    = tid >> 2;
    const int akq   = tid & 3;
    const int amt   = am >> 5;
    const int alc   = ((akq >> 1) << 5) | (am & 31);
    const int aboff = (akq & 1) * 8;

    f32x16 accq[2], acck[2];
#pragma unroll
    for (int mtx = 0; mtx < 2; ++mtx)
#pragma unroll
        for (int r = 0; r < 16; ++r) {
            accq[mtx][r] = 0.f;
            acck[mtx][r] = 0.f;
        }

    for (int kt = 0; kt < 16; ++kt) {
        const int k0 = kt * 16;
        __syncthreads();
#pragma unroll
        for (int mat = 0; mat < 2; ++mat) {
            const float* Wp = mat ? w_k : w_q;
            const float* wrow = Wp + (size_t)(k0 + wkh * 8) * Wn + n;
            float w8[8];
#pragma unroll
            for (int r = 0; r < 8; ++r)
                w8[r] = wrow[(size_t)r * Wn];
            f16x8 hi8, lo8;
#pragma unroll
            for (int e = 0; e < 8; ++e) {
                const float wv_ = w8[e];
                _Float16 hv = (_Float16)wv_;
                hi8[e] = hv;
                lo8[e] = (_Float16)(wv_ - (float)hv);
            }
            char* dplane = lds + LDS_B + (mat * 2) * 8192 + ntW * 1024;
            *(f16x8*)(dplane + wfo) = hi8;
            *(f16x8*)(dplane + 8192 + wfo) = lo8;
        }
        if (tid < 256) {
            const float4 xx = *(const float4*)(xbase + (size_t)am * Wn + k0 + akq * 4);
            f16x4 hi4, lo4;
            _Float16 t0 = (_Float16)xx.x; hi4[0] = t0; lo4[0] = (_Float16)(xx.x - (float)t0);
            _Float16 t1 = (_Float16)xx.y; hi4[1] = t1; lo4[1] = (_Float16)(xx.y - (float)t1);
            _Float16 t2 = (_Float16)xx.z; hi4[2] = t2; lo4[2] = (_Float16)(xx.z - (float)t2);
            _Float16 t3 = (_Float16)xx.w; hi4[3] = t3; lo4[3] = (_Float16)(xx.w - (float)t3);
            *(f16x4*)(lds + amt * 1024 + alc * 16 + aboff) = hi4;
            *(f16x4*)(lds + LDS_ALO + amt * 1024 + alc * 16 + aboff) = lo4;
        }
        __syncthreads();

        f16x8 ah[2], al[2];
#pragma unroll
        for (int mtx = 0; mtx < 2; ++mtx) {
            ah[mtx] = *(const f16x8*)(lds + mtx * 1024 + lane * 16);
            al[mtx] = *(const f16x8*)(lds + LDS_ALO + mtx * 1024 + lane * 16);
        }
        const char* bb = lds + LDS_B + ncol * 1024 + lane * 16;
        f16x8 bqh = *(const f16x8*)(bb + 0 * 8192);
        f16x8 bql = *(const f16x8*)(bb + 1 * 8192);
        f16x8 bkh = *(const f16x8*)(bb + 2 * 8192);
        f16x8 bkl = *(const f16x8*)(bb + 3 * 8192);
#pragma unroll
        for (int mtx = 0; mtx < 2; ++mtx) {
            accq[mtx] = MFMA(ah[mtx], bqh, accq[mtx]);
            accq[mtx] = MFMA(al[mtx], bqh, accq[mtx]);
            accq[mtx] = MFMA(ah[mtx], bql, accq[mtx]);
            acck[mtx] = MFMA(ah[mtx], bkh, acck[mtx]);
            acck[mtx] = MFMA(al[mtx], bkh, acck[mtx]);
            acck[mtx] = MFMA(ah[mtx], bkl, acck[mtx]);
        }
    }

    float* part    = (float*)(lds + 36864);
    float* combmax = (float*)(lds + 36864 + 2048);
    float* combsum = (float*)(lds + 36864 + 2304);

#pragma unroll
    for (int mtx = 0; mtx < 2; ++mtx)
#pragma unroll
        for (int r = 0; r < 16; ++r) {
            const int rl = (r & 3) + 8 * (r >> 2) + 4 * h;
            const int hh = h0 + mtx * 32 + rl;
            const int vv = ncol * 32 + l31;
            const size_t bidx = ((size_t)c * Hn + hh) * Wn + vv;
            const float qv = accq[mtx][r] + bq[bidx];
            const float kv = acck[mtx][r] + bk[bidx];
            accq[mtx][r] = qv * kv;
        }

#pragma unroll
    for (int mtx = 0; mtx < 2; ++mtx)
#pragma unroll
        for (int r = 0; r < 16; ++r) {
            float m2 = accq[mtx][r];
#pragma unroll
            for (int off = 16; off > 0; off >>= 1)
                m2 = fmaxf(m2, __shfl_xor(m2, off, 64));
            if ((lane & 15) == r && ((lane >> 4) & 1) == mtx) {
                const int rl  = (r & 3) + 8 * (r >> 2) + 4 * h;
                const int row = mtx * 32 + rl;
                part[ncol * 64 + row] = m2;
            }
        }
    __syncthreads();
    if (tid < 64) {
        float m = part[tid];
#pragma unroll
        for (int w = 1; w < 8; ++w)
            m = fmaxf(m, part[w * 64 + tid]);
        combmax[tid] = m;
    }
    __syncthreads();

#pragma unroll
    for (int mtx = 0; mtx < 2; ++mtx)
#pragma unroll
        for (int r = 0; r < 16; ++r) {
            const int rl  = (r & 3) + 8 * (r >> 2) + 4 * h;
            const int row = mtx * 32 + rl;
            const float mx = combmax[row];
            const float e0 = __expf(accq[mtx][r] - mx);
            accq[mtx][r] = e0;
            float ps = e0;
#pragma unroll
            for (int off = 16; off > 0; off >>= 1)
                ps += __shfl_xor(ps, off, 64);
            if ((lane & 15) == r && ((lane >> 4) & 1) == mtx)
                part[ncol * 64 + row] = ps;
        }
    __syncthreads();
    if (tid < 64) {
        float s = part[tid];
#pragma unroll
        for (int w = 1; w < 8; ++w)
            s += part[w * 64 + tid];
        combsum[tid] = s;
    }

    f32x16 accv[2];
#pragma unroll
    for (int mtx = 0; mtx < 2; ++mtx)
#pragma unroll
        for (int r = 0; r < 16; ++r)
            accv[mtx][r] = 0.f;

    for (int kt = 0; kt < 16; ++kt) {
        const int k0 = kt * 16;
        __syncthreads();
        {
            const float* wrow = w_v + (size_t)(k0 + wkh * 8) * Wn + n;
            float w8[8];
#pragma unroll
            for (int r = 0; r < 8; ++r)
                w8[r] = wrow[(size_t)r * Wn];
            f16x8 hi8;
#pragma unroll
            for (int e = 0; e < 8; ++e)
                hi8[e] = (_Float16)w8[e];
            *(f16x8*)(lds + LDS_B + ntW * 1024 + wfo) = hi8;
        }
        if (tid < 256) {
            const float4 xx = *(const float4*)(xbase + (size_t)am * Wn + k0 + akq * 4);
            f16x4 hi4;
            hi4[0] = (_Float16)xx.x;
            hi4[1] = (_Float16)xx.y;
            hi4[2] = (_Float16)xx.z;
            hi4[3] = (_Float16)xx.w;
            *(f16x4*)(lds + amt * 1024 + alc * 16 + aboff) = hi4;
        }
        __syncthreads();

        f16x8 ah[2];
#pragma unroll
        for (int mtx = 0; mtx < 2; ++mtx)
            ah[mtx] = *(const f16x8*)(lds + mtx * 1024 + lane * 16);
        f16x8 bvh = *(const f16x8*)(lds + LDS_B + ncol * 1024 + lane * 16);
#pragma unroll
        for (int mtx = 0; mtx < 2; ++mtx)
            accv[mtx] = MFMA(ah[mtx], bvh, accv[mtx]);
    }

    float* obase = out + ((size_t)(b * Cn + c) * Hn) * Wn;
#pragma unroll
    for (int mtx = 0; mtx < 2; ++mtx)
#pragma unroll
        for (int r = 0; r < 16; ++r) {
            const int rl  = (r & 3) + 8 * (r >> 2) + 4 * h;
            const int row = mtx * 32 + rl;
            const float inv = 1.0f / combsum[row];
            const int hh = h0 + row;
            const int vv = ncol * 32 + l31;
            const size_t bidx = ((size_t)c * Hn + hh) * Wn + vv;
            const float vx = accv[mtx][r] + bv[bidx];
            obase[(size_t)hh * Wn + vv] = accq[mtx][r] * vx * inv;
        }
}

extern "C" void kernel_launch(void* const* d_in, const int* in_sizes, int n_in,
                              void* d_out, int out_size, void* d_ws, size_t ws_size,
                              hipStream_t stream) {
    (void)in_sizes; (void)n_in; (void)out_size;
    const float* x  = (const float*)d_in[0];
    const float* wq = (const float*)d_in[1];
    const float* wk = (const float*)d_in[2];
    const float* wv = (const float*)d_in[3];
    const float* bq = (const float*)d_in[4];
    const float* bk = (const float*)d_in[5];
    const float* bv = (const float*)d_in[6];
    float* out = (float*)d_out;

    if (d_ws != nullptr && ws_size >= WS_NEED) {
        hipLaunchKernelGGL(prep_w, dim3(Cn * 16), dim3(256), 0, stream,
                           wq, wk, wv, (_Float16*)d_ws);
        hipLaunchKernelGGL(axile_attn_pipe, dim3(Bn * 4 * Cn), dim3(1024), 0, stream,
                           x, (const _Float16*)d_ws, bq, bk, bv, out);
    } else {
        hipLaunchKernelGGL(axile_attn_mfma4, dim3(Bn * 4 * Cn), dim3(512), 0, stream,
                           x, wq, wk, wv, bq, bk, bv, out);
    }
}

// Round 6
// 481.306 us; speedup vs baseline: 1.1620x; 1.1620x over previous
//
#include <hip/hip_runtime.h>
#include <math.h>

// AxileAttention: out = softmax((X@Wq+bq)*(X@Wk+bk), -1) * (X@Wv+bv), per (b,c).
// B=8 C=64 H=256 W=256, fp32 in/out.
//
// Round 13: X fully staged in LDS once. R12 post-mortem: counted-vmcnt was
// correct but neutral (358us = R11) -> shared defect of R11/R12 vs R10: the
// per-lane 1024B-strided X loads (64 cache lines per wave-instr, x8 duplicate
// waves ~ 2K line-lookups/iter through the L1/TA pipe). Fix: prologue loads
// the 64-row X tile LINEARLY coalesced (thread i <- 16B at linear i*16; 16
// lines/wave-instr), converts to hi/lo f16 fragment slots (2064B-padded kt
// stride to spread write banks). K-loop is pure LDS: 2 A + 5 B ds_read_b128
// + 7 MFMA + W global_load_lds (2-buf; vmcnt(0) sits ~1Kcyc after issue).
// LDS 2x33KB X + 2x40KB W = 144.5KB -> 1 block/CU, 16 waves. Barriers: 17.
// prep_w (W->f16 hi/lo fragment planes in d_ws) unchanged; R8 fallback kept.

#define Bn 8
#define Cn 64
#define Hn 256
#define Wn 256

typedef _Float16 f16x8 __attribute__((ext_vector_type(8)));
typedef _Float16 f16x4 __attribute__((ext_vector_type(4)));
typedef float    f32x16 __attribute__((ext_vector_type(16)));

#define MFMA(a, b, c) __builtin_amdgcn_mfma_f32_32x32x16_f16((a), (b), (c), 0, 0, 0)

// ws layout: plane(c,kt,p) = ((c*16+kt)*5+p) * 8192 bytes, p: 0=qh 1=ql 2=kh 3=kl 4=vh
// within plane: ntile*1024 + (khalf*32+nl)*16 bytes = f16x8 of rows k0+khalf*8..+8 at col n
// Planes of one kt contiguous: one 40960B tile per (c,kt).
#define WS_PLANE_H 4096   // _Float16 elements per plane (8192 B)
#define WS_NEED ((size_t)Cn * 16 * 5 * 8192)
#define FTILE 40960       // 5 planes * 8192 B

// main-kernel LDS map (total 147968 B -> 1 block/CU):
//   XHI: [0, 33024)            kt*XSTRIDE + slot*16 ; slot=(row>>5)*64+h*32+(row&31)
//   XLO: [33024, 66048)
//   W dbuf: [66048, 147968)    two FTILE buffers
//   softmax scratch aliases XHI after the loop.
#define XSTRIDE 2064      // 2048 + 16 pad: spreads write banks across kt areas
#define XLO_OFF 33024     // 16*XSTRIDE
#define WB0     66048

__device__ __forceinline__ void ldst16(const void* g, void* l) {
    __builtin_amdgcn_global_load_lds(
        (const __attribute__((address_space(1))) unsigned int*)g,
        (__attribute__((address_space(3))) unsigned int*)l, 16, 0, 0);
}

__device__ __forceinline__ void cvt_hilo4(const float4 a, f16x4& hi, f16x4& lo) {
    float v[4] = {a.x, a.y, a.z, a.w};
#pragma unroll
    for (int e = 0; e < 4; ++e) {
        _Float16 hv = (_Float16)v[e];
        hi[e] = hv;
        lo[e] = (_Float16)(v[e] - (float)hv);
    }
}

// ---------------- prep: W (f32) -> fragment-ordered f16 hi/lo planes ----------------
__global__ __launch_bounds__(256) void prep_w(
    const float* __restrict__ wq, const float* __restrict__ wk,
    const float* __restrict__ wv, _Float16* __restrict__ wf)
{
    const int blk = blockIdx.x;          // c*16 + kt
    const int kt  = blk & 15;
    const int c   = blk >> 4;
    const int n   = threadIdx.x;         // column 0..255
    const int ntile = n >> 5;
    const int nl    = n & 31;

    _Float16* base = wf + (size_t)blk * 5 * WS_PLANE_H;
    const size_t woff = ((size_t)c * Wn + kt * 16) * Wn + n;

#pragma unroll
    for (int mat = 0; mat < 2; ++mat) {      // 0=q, 1=k : hi+lo planes
        const float* Wp = (mat ? wk : wq) + woff;
        float w16[16];
#pragma unroll
        for (int r = 0; r < 16; ++r)
            w16[r] = Wp[(size_t)r * Wn];
        _Float16* hip = base + (mat * 2) * WS_PLANE_H + ntile * 512;
        _Float16* lop = hip + WS_PLANE_H;
#pragma unroll
        for (int h2 = 0; h2 < 2; ++h2) {
            f16x8 hi8, lo8;
#pragma unroll
            for (int e = 0; e < 8; ++e) {
                const float wv_ = w16[h2 * 8 + e];
                _Float16 hv = (_Float16)wv_;
                hi8[e] = hv;
                lo8[e] = (_Float16)(wv_ - (float)hv);
            }
            *(f16x8*)(hip + (h2 * 32 + nl) * 8) = hi8;
            *(f16x8*)(lop + (h2 * 32 + nl) * 8) = lo8;
        }
    }
    {   // v: hi only (plane 4)
        const float* Wp = wv + woff;
        float w16[16];
#pragma unroll
        for (int r = 0; r < 16; ++r)
            w16[r] = Wp[(size_t)r * Wn];
        _Float16* vp = base + 4 * WS_PLANE_H + ntile * 512;
#pragma unroll
        for (int h2 = 0; h2 < 2; ++h2) {
            f16x8 hi8;
#pragma unroll
            for (int e = 0; e < 8; ++e)
                hi8[e] = (_Float16)w16[h2 * 8 + e];
            *(f16x8*)(vp + (h2 * 32 + nl) * 8) = hi8;
        }
    }
}

// ---------------- main: fused, M=64, X-in-LDS, W 2-buf pipeline ----------------
__global__ __launch_bounds__(1024, 1) void axile_attn_xlds(
    const float* __restrict__ x,
    const _Float16* __restrict__ wf,
    const float* __restrict__ bq,
    const float* __restrict__ bk,
    const float* __restrict__ bv,
    float* __restrict__ out)
{
    __shared__ __align__(16) char lds[147968];

    const int tid   = threadIdx.x;
    const int lane  = tid & 63;
    const int h     = lane >> 5;
    const int l31   = lane & 31;
    const int wv_id = tid >> 6;        // 0..15
    const int ncol  = wv_id & 7;       // 32-col strip
    const int mt    = wv_id >> 3;      // 32-row half of the 64-row tile

    // blk = (ht*8 + b)*64 + c : c low bits -> XCD affinity per channel.
    const int blk = blockIdx.x;
    const int c   = blk & 63;
    const int j   = blk >> 6;          // ht*8 + b
    const int b   = j & 7;
    const int h0  = (j >> 3) * 64;

    const char* wfc = (const char*)(wf + (size_t)c * 16 * 5 * WS_PLANE_H);

    // W staging split: 40960 B / (1024 thr * 16 B) = 2.5 rounds
    const bool halfw = (tid < 512);
    const int  so0 = tid * 16;
    const int  so1 = 16384 + tid * 16;
    const int  so2 = 32768 + tid * 16;

    f32x16 accq, acck, accv;
#pragma unroll
    for (int r = 0; r < 16; ++r) {
        accq[r] = 0.f;
        acck[r] = 0.f;
        accv[r] = 0.f;
    }

    // ---- prologue: linear-coalesced X tile -> LDS hi/lo; W(0) -> WB0 ----
    {
        const char* xg = (const char*)(x + ((size_t)(b * Cn + c) * Hn + h0) * Wn);
        float4 xv0 = *(const float4*)(xg + (size_t)tid * 16);
        float4 xv1 = *(const float4*)(xg + (size_t)(tid + 1024) * 16);
        float4 xv2 = *(const float4*)(xg + (size_t)(tid + 2048) * 16);
        float4 xv3 = *(const float4*)(xg + (size_t)(tid + 3072) * 16);
        // W(0) stage (in flight during conversion)
        ldst16(wfc + so0, lds + WB0 + so0);
        ldst16(wfc + so1, lds + WB0 + so1);
        if (halfw) ldst16(wfc + so2, lds + WB0 + so2);

        // thread's 4 float4 = rows (tid>>6)+16i, cols k0..k0+3, k0=(tid&63)*4
        const int k0  = (tid & 63) * 4;
        const int xkt = k0 >> 4;
        const int hp  = (k0 >> 3) & 1;
        const int bo  = (k0 & 7) * 2;      // byte offset within 16B slot: 0 or 8
        const int xbase = xkt * XSTRIDE + bo;
        float4 xv[4] = {xv0, xv1, xv2, xv3};
#pragma unroll
        for (int i = 0; i < 4; ++i) {
            const int r    = (tid >> 6) + i * 16;
            const int slot = (r >> 5) * 64 + hp * 32 + (r & 31);
            f16x4 h4, l4;
            cvt_hilo4(xv[i], h4, l4);
            *(f16x4*)(lds + xbase + slot * 16) = h4;
            *(f16x4*)(lds + XLO_OFF + xbase + slot * 16) = l4;
        }
        asm volatile("s_waitcnt vmcnt(0)" ::: "memory");
        __builtin_amdgcn_s_barrier();
        __builtin_amdgcn_sched_barrier(0);
    }

    // ================= fused K-loop: 16 iters, pure-LDS compute =================
    const int aslot = (mt * 64 + h * 32 + l31) * 16;
    int o_cur = WB0, o_nxt = WB0 + FTILE;
    for (int kt = 0; kt < 16; ++kt) {
        if (kt < 15) {   // stage W(kt+1); ~1Kcyc of compute before the drain
            const char* ssrc = wfc + (size_t)(kt + 1) * FTILE;
            ldst16(ssrc + so0, lds + o_nxt + so0);
            ldst16(ssrc + so1, lds + o_nxt + so1);
            if (halfw) ldst16(ssrc + so2, lds + o_nxt + so2);
        }

        const f16x8 ah = *(const f16x8*)(lds + kt * XSTRIDE + aslot);
        const f16x8 al = *(const f16x8*)(lds + XLO_OFF + kt * XSTRIDE + aslot);
        const char* bb = lds + o_cur + ncol * 1024 + lane * 16;
        const f16x8 bqh = *(const f16x8*)(bb);
        const f16x8 bql = *(const f16x8*)(bb + 8192);
        const f16x8 bkh = *(const f16x8*)(bb + 16384);
        const f16x8 bkl = *(const f16x8*)(bb + 24576);
        const f16x8 bvh = *(const f16x8*)(bb + 32768);

        accq = MFMA(ah, bqh, accq);
        accq = MFMA(al, bqh, accq);
        accq = MFMA(ah, bql, accq);
        acck = MFMA(ah, bkh, acck);
        acck = MFMA(al, bkh, acck);
        acck = MFMA(ah, bkl, acck);
        accv = MFMA(ah, bvh, accv);

        asm volatile("s_waitcnt vmcnt(0)" ::: "memory");   // own W(kt+1) staged
        __builtin_amdgcn_s_barrier();
        __builtin_amdgcn_sched_barrier(0);
        const int t = o_cur; o_cur = o_nxt; o_nxt = t;
    }

    // ---- softmax scratch aliases XHI (all loop LDS reads retired) ----
    float* part    = (float*)lds;            // [8 nstrips][64 rows]
    float* combmax = (float*)(lds + 2048);   // [64]
    float* combsum = (float*)(lds + 2304);   // [64]

    // ---- s = (q+bq)*(k+bk) into accq ----
#pragma unroll
    for (int r = 0; r < 16; ++r) {
        const int row = mt * 32 + (r & 3) + 8 * (r >> 2) + 4 * h;
        const int vv  = ncol * 32 + l31;
        const size_t bidx = ((size_t)c * Hn + h0 + row) * Wn + vv;
        const float qv = accq[r] + bq[bidx];
        const float kv = acck[r] + bk[bidx];
        accq[r] = qv * kv;
    }

    // ---- row max (reduce over l31; h halves separate) ----
#pragma unroll
    for (int r = 0; r < 16; ++r) {
        float m2 = accq[r];
#pragma unroll
        for (int off = 16; off > 0; off >>= 1)
            m2 = fmaxf(m2, __shfl_xor(m2, off, 64));
        if ((lane & 31) == r) {
            const int row = mt * 32 + (r & 3) + 8 * (r >> 2) + 4 * h;
            part[ncol * 64 + row] = m2;
        }
    }
    __syncthreads();
    if (tid < 64) {
        float m = part[tid];
#pragma unroll
        for (int w = 1; w < 8; ++w)
            m = fmaxf(m, part[w * 64 + tid]);
        combmax[tid] = m;
    }
    __syncthreads();

    // ---- e = exp(s - mx); row sum ----
#pragma unroll
    for (int r = 0; r < 16; ++r) {
        const int row = mt * 32 + (r & 3) + 8 * (r >> 2) + 4 * h;
        const float mx = combmax[row];
        const float e0 = __expf(accq[r] - mx);
        accq[r] = e0;
        float ps = e0;
#pragma unroll
        for (int off = 16; off > 0; off >>= 1)
            ps += __shfl_xor(ps, off, 64);
        if ((lane & 31) == r)
            part[ncol * 64 + row] = ps;
    }
    __syncthreads();
    if (tid < 64) {
        float s = part[tid];
#pragma unroll
        for (int w = 1; w < 8; ++w)
            s += part[w * 64 + tid];
        combsum[tid] = s;
    }
    __syncthreads();

    // ---- out = e * (v + bv) / sum ----
    float* obase = out + ((size_t)(b * Cn + c) * Hn) * Wn;
#pragma unroll
    for (int r = 0; r < 16; ++r) {
        const int row = mt * 32 + (r & 3) + 8 * (r >> 2) + 4 * h;
        const float inv = 1.0f / combsum[row];
        const int hh = h0 + row;
        const int vv = ncol * 32 + l31;
        const size_t bidx = ((size_t)c * Hn + hh) * Wn + vv;
        const float vx = accv[r] + bv[bidx];
        obase[(size_t)hh * Wn + vv] = accq[r] * vx * inv;
    }
}

// ---------------- fallback (R8): in-kernel W conversion, no ws ----------------
#define LDS_ALO 2048
#define LDS_B   4096

__global__ __launch_bounds__(512, 4) void axile_attn_mfma4(
    const float* __restrict__ x,
    const float* __restrict__ wq,
    const float* __restrict__ wk,
    const float* __restrict__ wv,
    const float* __restrict__ bq,
    const float* __restrict__ bk,
    const float* __restrict__ bv,
    float* __restrict__ out)
{
    __shared__ __align__(16) char lds[39424];

    const int tid  = threadIdx.x;
    const int ncol = tid >> 6;
    const int lane = tid & 63;
    const int h    = lane >> 5;
    const int l31  = lane & 31;

    const int blk = blockIdx.x;
    const int c   = blk & 63;
    const int j   = blk >> 6;
    const int b   = j & 7;
    const int h0  = (j >> 3) * 64;

    const float* xbase = x + ((size_t)(b * Cn + c) * Hn + h0) * Wn;
    const float* w_q = wq + (size_t)c * Wn * Wn;
    const float* w_k = wk + (size_t)c * Wn * Wn;
    const float* w_v = wv + (size_t)c * Wn * Wn;

    const int wkh = tid >> 8;
    const int n   = tid & 255;
    const int ntW = n >> 5;
    const int nl  = n & 31;
    const int wfo = ((wkh << 5) | nl) * 16;
    const int am    = tid >> 2;
    const int akq   = tid & 3;
    const int amt   = am >> 5;
    const int alc   = ((akq >> 1) << 5) | (am & 31);
    const int aboff = (akq & 1) * 8;

    f32x16 accq[2], acck[2];
#pragma unroll
    for (int mtx = 0; mtx < 2; ++mtx)
#pragma unroll
        for (int r = 0; r < 16; ++r) {
            accq[mtx][r] = 0.f;
            acck[mtx][r] = 0.f;
        }

    for (int kt = 0; kt < 16; ++kt) {
        const int k0 = kt * 16;
        __syncthreads();
#pragma unroll
        for (int mat = 0; mat < 2; ++mat) {
            const float* Wp = mat ? w_k : w_q;
            const float* wrow = Wp + (size_t)(k0 + wkh * 8) * Wn + n;
            float w8[8];
#pragma unroll
            for (int r = 0; r < 8; ++r)
                w8[r] = wrow[(size_t)r * Wn];
            f16x8 hi8, lo8;
#pragma unroll
            for (int e = 0; e < 8; ++e) {
                const float wv_ = w8[e];
                _Float16 hv = (_Float16)wv_;
                hi8[e] = hv;
                lo8[e] = (_Float16)(wv_ - (float)hv);
            }
            char* dplane = lds + LDS_B + (mat * 2) * 8192 + ntW * 1024;
            *(f16x8*)(dplane + wfo) = hi8;
            *(f16x8*)(dplane + 8192 + wfo) = lo8;
        }
        if (tid < 256) {
            const float4 xx = *(const float4*)(xbase + (size_t)am * Wn + k0 + akq * 4);
            f16x4 hi4, lo4;
            _Float16 t0 = (_Float16)xx.x; hi4[0] = t0; lo4[0] = (_Float16)(xx.x - (float)t0);
            _Float16 t1 = (_Float16)xx.y; hi4[1] = t1; lo4[1] = (_Float16)(xx.y - (float)t1);
            _Float16 t2 = (_Float16)xx.z; hi4[2] = t2; lo4[2] = (_Float16)(xx.z - (float)t2);
            _Float16 t3 = (_Float16)xx.w; hi4[3] = t3; lo4[3] = (_Float16)(xx.w - (float)t3);
            *(f16x4*)(lds + amt * 1024 + alc * 16 + aboff) = hi4;
            *(f16x4*)(lds + LDS_ALO + amt * 1024 + alc * 16 + aboff) = lo4;
        }
        __syncthreads();

        f16x8 ah[2], al[2];
#pragma unroll
        for (int mtx = 0; mtx < 2; ++mtx) {
            ah[mtx] = *(const f16x8*)(lds + mtx * 1024 + lane * 16);
            al[mtx] = *(const f16x8*)(lds + LDS_ALO + mtx * 1024 + lane * 16);
        }
        const char* bb = lds + LDS_B + ncol * 1024 + lane * 16;
        f16x8 bqh = *(const f16x8*)(bb + 0 * 8192);
        f16x8 bql = *(const f16x8*)(bb + 1 * 8192);
        f16x8 bkh = *(const f16x8*)(bb + 2 * 8192);
        f16x8 bkl = *(const f16x8*)(bb + 3 * 8192);
#pragma unroll
        for (int mtx = 0; mtx < 2; ++mtx) {
            accq[mtx] = MFMA(ah[mtx], bqh, accq[mtx]);
            accq[mtx] = MFMA(al[mtx], bqh, accq[mtx]);
            accq[mtx] = MFMA(ah[mtx], bql, accq[mtx]);
            acck[mtx] = MFMA(ah[mtx], bkh, acck[mtx]);
            acck[mtx] = MFMA(al[mtx], bkh, acck[mtx]);
            acck[mtx] = MFMA(ah[mtx], bkl, acck[mtx]);
        }
    }

    float* part    = (float*)(lds + 36864);
    float* combmax = (float*)(lds + 36864 + 2048);
    float* combsum = (float*)(lds + 36864 + 2304);

#pragma unroll
    for (int mtx = 0; mtx < 2; ++mtx)
#pragma unroll
        for (int r = 0; r < 16; ++r) {
            const int rl = (r & 3) + 8 * (r >> 2) + 4 * h;
            const int hh = h0 + mtx * 32 + rl;
            const int vv = ncol * 32 + l31;
            const size_t bidx = ((size_t)c * Hn + hh) * Wn + vv;
            const float qv = accq[mtx][r] + bq[bidx];
            const float kv = acck[mtx][r] + bk[bidx];
            accq[mtx][r] = qv * kv;
        }

#pragma unroll
    for (int mtx = 0; mtx < 2; ++mtx)
#pragma unroll
        for (int r = 0; r < 16; ++r) {
            float m2 = accq[mtx][r];
#pragma unroll
            for (int off = 16; off > 0; off >>= 1)
                m2 = fmaxf(m2, __shfl_xor(m2, off, 64));
            if ((lane & 15) == r && ((lane >> 4) & 1) == mtx) {
                const int rl  = (r & 3) + 8 * (r >> 2) + 4 * h;
                const int row = mtx * 32 + rl;
                part[ncol * 64 + row] = m2;
            }
        }
    __syncthreads();
    if (tid < 64) {
        float m = part[tid];
#pragma unroll
        for (int w = 1; w < 8; ++w)
            m = fmaxf(m, part[w * 64 + tid]);
        combmax[tid] = m;
    }
    __syncthreads();

#pragma unroll
    for (int mtx = 0; mtx < 2; ++mtx)
#pragma unroll
        for (int r = 0; r < 16; ++r) {
            const int rl  = (r & 3) + 8 * (r >> 2) + 4 * h;
            const int row = mtx * 32 + rl;
            const float mx = combmax[row];
            const float e0 = __expf(accq[mtx][r] - mx);
            accq[mtx][r] = e0;
            float ps = e0;
#pragma unroll
            for (int off = 16; off > 0; off >>= 1)
                ps += __shfl_xor(ps, off, 64);
            if ((lane & 15) == r && ((lane >> 4) & 1) == mtx)
                part[ncol * 64 + row] = ps;
        }
    __syncthreads();
    if (tid < 64) {
        float s = part[tid];
#pragma unroll
        for (int w = 1; w < 8; ++w)
            s += part[w * 64 + tid];
        combsum[tid] = s;
    }

    f32x16 accv[2];
#pragma unroll
    for (int mtx = 0; mtx < 2; ++mtx)
#pragma unroll
        for (int r = 0; r < 16; ++r)
            accv[mtx][r] = 0.f;

    for (int kt = 0; kt < 16; ++kt) {
        const int k0 = kt * 16;
        __syncthreads();
        {
            const float* wrow = w_v + (size_t)(k0 + wkh * 8) * Wn + n;
            float w8[8];
#pragma unroll
            for (int r = 0; r < 8; ++r)
                w8[r] = wrow[(size_t)r * Wn];
            f16x8 hi8;
#pragma unroll
            for (int e = 0; e < 8; ++e)
                hi8[e] = (_Float16)w8[e];
            *(f16x8*)(lds + LDS_B + ntW * 1024 + wfo) = hi8;
        }
        if (tid < 256) {
            const float4 xx = *(const float4*)(xbase + (size_t)am * Wn + k0 + akq * 4);
            f16x4 hi4;
            hi4[0] = (_Float16)xx.x;
            hi4[1] = (_Float16)xx.y;
            hi4[2] = (_Float16)xx.z;
            hi4[3] = (_Float16)xx.w;
            *(f16x4*)(lds + amt * 1024 + alc * 16 + aboff) = hi4;
        }
        __syncthreads();

        f16x8 ah[2];
#pragma unroll
        for (int mtx = 0; mtx < 2; ++mtx)
            ah[mtx] = *(const f16x8*)(lds + mtx * 1024 + lane * 16);
        f16x8 bvh = *(const f16x8*)(lds + LDS_B + ncol * 1024 + lane * 16);
#pragma unroll
        for (int mtx = 0; mtx < 2; ++mtx)
            accv[mtx] = MFMA(ah[mtx], bvh, accv[mtx]);
    }

    float* obase = out + ((size_t)(b * Cn + c) * Hn) * Wn;
#pragma unroll
    for (int mtx = 0; mtx < 2; ++mtx)
#pragma unroll
        for (int r = 0; r < 16; ++r) {
            const int rl  = (r & 3) + 8 * (r >> 2) + 4 * h;
            const int row = mtx * 32 + rl;
            const float inv = 1.0f / combsum[row];
            const int hh = h0 + row;
            const int vv = ncol * 32 + l31;
            const size_t bidx = ((size_t)c * Hn + hh) * Wn + vv;
            const float vx = accv[mtx][r] + bv[bidx];
            obase[(size_t)hh * Wn + vv] = accq[mtx][r] * vx * inv;
        }
}

extern "C" void kernel_launch(void* const* d_in, const int* in_sizes, int n_in,
                              void* d_out, int out_size, void* d_ws, size_t ws_size,
                              hipStream_t stream) {
    (void)in_sizes; (void)n_in; (void)out_size;
    const float* x  = (const float*)d_in[0];
    const float* wq = (const float*)d_in[1];
    const float* wk = (const float*)d_in[2];
    const float* wv = (const float*)d_in[3];
    const float* bq = (const float*)d_in[4];
    const float* bk = (const float*)d_in[5];
    const float* bv = (const float*)d_in[6];
    float* out = (float*)d_out;

    if (d_ws != nullptr && ws_size >= WS_NEED) {
        hipLaunchKernelGGL(prep_w, dim3(Cn * 16), dim3(256), 0, stream,
                           wq, wk, wv, (_Float16*)d_ws);
        hipLaunchKernelGGL(axile_attn_xlds, dim3(Bn * 4 * Cn), dim3(1024), 0, stream,
                           x, (const _Float16*)d_ws, bq, bk, bv, out);
    } else {
        hipLaunchKernelGGL(axile_attn_mfma4, dim3(Bn * 4 * Cn), dim3(512), 0, stream,
                           x, wq, wk, wv, bq, bk, bv, out);
    }
}

// Round 7
// 459.819 us; speedup vs baseline: 1.2163x; 1.0467x over previous
//
#include <hip/hip_runtime.h>
#include <math.h>

// AxileAttention: out = softmax((X@Wq+bq)*(X@Wk+bk), -1) * (X@Wv+bv), per (b,c).
// B=8 C=64 H=256 W=256, fp32 in/out.
//
// Round 14: R13 skeleton (X staged once in LDS, fused 7-MFMA K-loop, W 2-buf
// DMA) + two targeted cuts found by cycle audit (5.3K cyc/iter observed vs
// ~2K demand):
//  1. Epilogue reductions via DPP: __shfl_xor chains were ds_bpermute -> 2560
//     LDS-unit ops/block (~= the whole K-loop's 1792 reads). Now 4x
//     update_dpp(ROW_ROR 1/2/4/8)+op (pure VALU) + 1 ds_swizzle(xor16).
//  2. A-read software pipeline: X region is static, so A(kt+1) ds_reads issue
//     BEFORE the vmcnt(0)+barrier; post-barrier path is only the 5 B reads.
// prep_w (W->f16 hi/lo fragment planes in d_ws) unchanged; R8 fallback kept.

#define Bn 8
#define Cn 64
#define Hn 256
#define Wn 256

typedef _Float16 f16x8 __attribute__((ext_vector_type(8)));
typedef _Float16 f16x4 __attribute__((ext_vector_type(4)));
typedef float    f32x16 __attribute__((ext_vector_type(16)));

#define MFMA(a, b, c) __builtin_amdgcn_mfma_f32_32x32x16_f16((a), (b), (c), 0, 0, 0)

// ws layout: plane(c,kt,p) = ((c*16+kt)*5+p) * 8192 bytes, p: 0=qh 1=ql 2=kh 3=kl 4=vh
#define WS_PLANE_H 4096   // _Float16 elements per plane (8192 B)
#define WS_NEED ((size_t)Cn * 16 * 5 * 8192)
#define FTILE 40960       // 5 planes * 8192 B

// main-kernel LDS map (147968 B -> 1 block/CU):
//   XHI: [0, 33024)   kt*XSTRIDE + slot*16 ; slot=(row>>5)*64+h*32+(row&31)
//   XLO: [33024, 66048)
//   W dbuf: [66048, 147968)
//   softmax scratch aliases XHI[0..2304) after the loop (no overlap with
//   kt=15 A-reads at 30960+ or W bufs at 66048+).
#define XSTRIDE 2064
#define XLO_OFF 33024
#define WB0     66048

__device__ __forceinline__ void ldst16(const void* g, void* l) {
    __builtin_amdgcn_global_load_lds(
        (const __attribute__((address_space(1))) unsigned int*)g,
        (__attribute__((address_space(3))) unsigned int*)l, 16, 0, 0);
}

__device__ __forceinline__ void cvt_hilo4(const float4 a, f16x4& hi, f16x4& lo) {
    float v[4] = {a.x, a.y, a.z, a.w};
#pragma unroll
    for (int e = 0; e < 4; ++e) {
        _Float16 hv = (_Float16)v[e];
        hi[e] = hv;
        lo[e] = (_Float16)(v[e] - (float)hv);
    }
}

// DPP helpers: rotate within 16-lane rows (VALU), then bridge 16<->16 inside
// each 32-lane half with one ds_swizzle (offset 0x401F = xor lane^16).
__device__ __forceinline__ float dpp_ror(float v, int ctrl_unused, int code) {
    // wrapper not used; explicit macros below (ctrl must be literal)
    return v;
}
#define DPP_STEP_MAX(v, CTRL)                                                  \
    v = fmaxf(v, __builtin_bit_cast(float, __builtin_amdgcn_update_dpp(       \
            0, __builtin_bit_cast(int, v), CTRL, 0xF, 0xF, true)))
#define DPP_STEP_ADD(v, CTRL)                                                  \
    v = v + __builtin_bit_cast(float, __builtin_amdgcn_update_dpp(            \
            0, __builtin_bit_cast(int, v), CTRL, 0xF, 0xF, true))

__device__ __forceinline__ float rowmax32(float v) {
    DPP_STEP_MAX(v, 0x121);   // row_ror:1
    DPP_STEP_MAX(v, 0x122);   // row_ror:2
    DPP_STEP_MAX(v, 0x124);   // row_ror:4
    DPP_STEP_MAX(v, 0x128);   // row_ror:8
    float o = __builtin_bit_cast(float, __builtin_amdgcn_ds_swizzle(
                  __builtin_bit_cast(int, v), 0x401F));
    return fmaxf(v, o);
}
__device__ __forceinline__ float rowsum32(float v) {
    DPP_STEP_ADD(v, 0x121);
    DPP_STEP_ADD(v, 0x122);
    DPP_STEP_ADD(v, 0x124);
    DPP_STEP_ADD(v, 0x128);
    float o = __builtin_bit_cast(float, __builtin_amdgcn_ds_swizzle(
                  __builtin_bit_cast(int, v), 0x401F));
    return v + o;
}

// ---------------- prep: W (f32) -> fragment-ordered f16 hi/lo planes ----------------
__global__ __launch_bounds__(256) void prep_w(
    const float* __restrict__ wq, const float* __restrict__ wk,
    const float* __restrict__ wv, _Float16* __restrict__ wf)
{
    const int blk = blockIdx.x;          // c*16 + kt
    const int kt  = blk & 15;
    const int c   = blk >> 4;
    const int n   = threadIdx.x;         // column 0..255
    const int ntile = n >> 5;
    const int nl    = n & 31;

    _Float16* base = wf + (size_t)blk * 5 * WS_PLANE_H;
    const size_t woff = ((size_t)c * Wn + kt * 16) * Wn + n;

#pragma unroll
    for (int mat = 0; mat < 2; ++mat) {      // 0=q, 1=k : hi+lo planes
        const float* Wp = (mat ? wk : wq) + woff;
        float w16[16];
#pragma unroll
        for (int r = 0; r < 16; ++r)
            w16[r] = Wp[(size_t)r * Wn];
        _Float16* hip = base + (mat * 2) * WS_PLANE_H + ntile * 512;
        _Float16* lop = hip + WS_PLANE_H;
#pragma unroll
        for (int h2 = 0; h2 < 2; ++h2) {
            f16x8 hi8, lo8;
#pragma unroll
            for (int e = 0; e < 8; ++e) {
                const float wv_ = w16[h2 * 8 + e];
                _Float16 hv = (_Float16)wv_;
                hi8[e] = hv;
                lo8[e] = (_Float16)(wv_ - (float)hv);
            }
            *(f16x8*)(hip + (h2 * 32 + nl) * 8) = hi8;
            *(f16x8*)(lop + (h2 * 32 + nl) * 8) = lo8;
        }
    }
    {   // v: hi only (plane 4)
        const float* Wp = wv + woff;
        float w16[16];
#pragma unroll
        for (int r = 0; r < 16; ++r)
            w16[r] = Wp[(size_t)r * Wn];
        _Float16* vp = base + 4 * WS_PLANE_H + ntile * 512;
#pragma unroll
        for (int h2 = 0; h2 < 2; ++h2) {
            f16x8 hi8;
#pragma unroll
            for (int e = 0; e < 8; ++e)
                hi8[e] = (_Float16)w16[h2 * 8 + e];
            *(f16x8*)(vp + (h2 * 32 + nl) * 8) = hi8;
        }
    }
}

// ---------------- main: fused, M=64, X-in-LDS, W 2-buf, A-prefetch, DPP-epilogue ----
__global__ __launch_bounds__(1024, 1) void axile_attn_xlds2(
    const float* __restrict__ x,
    const _Float16* __restrict__ wf,
    const float* __restrict__ bq,
    const float* __restrict__ bk,
    const float* __restrict__ bv,
    float* __restrict__ out)
{
    __shared__ __align__(16) char lds[147968];

    const int tid   = threadIdx.x;
    const int lane  = tid & 63;
    const int h     = lane >> 5;
    const int l31   = lane & 31;
    const int wv_id = tid >> 6;        // 0..15
    const int ncol  = wv_id & 7;       // 32-col strip
    const int mt    = wv_id >> 3;      // 32-row half of the 64-row tile

    const int blk = blockIdx.x;
    const int c   = blk & 63;
    const int j   = blk >> 6;          // ht*8 + b
    const int b   = j & 7;
    const int h0  = (j >> 3) * 64;

    const char* wfc = (const char*)(wf + (size_t)c * 16 * 5 * WS_PLANE_H);

    const bool halfw = (tid < 512);
    const int  so0 = tid * 16;
    const int  so1 = 16384 + tid * 16;
    const int  so2 = 32768 + tid * 16;

    f32x16 accq, acck, accv;
#pragma unroll
    for (int r = 0; r < 16; ++r) {
        accq[r] = 0.f;
        acck[r] = 0.f;
        accv[r] = 0.f;
    }

    // ---- prologue: linear-coalesced X tile -> LDS hi/lo; W(0) -> WB0 ----
    {
        const char* xg = (const char*)(x + ((size_t)(b * Cn + c) * Hn + h0) * Wn);
        float4 xv0 = *(const float4*)(xg + (size_t)tid * 16);
        float4 xv1 = *(const float4*)(xg + (size_t)(tid + 1024) * 16);
        float4 xv2 = *(const float4*)(xg + (size_t)(tid + 2048) * 16);
        float4 xv3 = *(const float4*)(xg + (size_t)(tid + 3072) * 16);
        ldst16(wfc + so0, lds + WB0 + so0);
        ldst16(wfc + so1, lds + WB0 + so1);
        if (halfw) ldst16(wfc + so2, lds + WB0 + so2);

        const int k0  = (tid & 63) * 4;
        const int xkt = k0 >> 4;
        const int hp  = (k0 >> 3) & 1;
        const int bo  = (k0 & 7) * 2;
        const int xbase = xkt * XSTRIDE + bo;
        float4 xv[4] = {xv0, xv1, xv2, xv3};
#pragma unroll
        for (int i = 0; i < 4; ++i) {
            const int r    = (tid >> 6) + i * 16;
            const int slot = (r >> 5) * 64 + hp * 32 + (r & 31);
            f16x4 h4, l4;
            cvt_hilo4(xv[i], h4, l4);
            *(f16x4*)(lds + xbase + slot * 16) = h4;
            *(f16x4*)(lds + XLO_OFF + xbase + slot * 16) = l4;
        }
        asm volatile("s_waitcnt vmcnt(0)" ::: "memory");
        __builtin_amdgcn_s_barrier();
        __builtin_amdgcn_sched_barrier(0);
    }

    // ================= fused K-loop: A(kt+1) prefetched pre-barrier =================
    const int aslot = (mt * 64 + h * 32 + l31) * 16;
    f16x8 ah = *(const f16x8*)(lds + aslot);             // A(0)
    f16x8 al = *(const f16x8*)(lds + XLO_OFF + aslot);
    int o_cur = WB0, o_nxt = WB0 + FTILE;
    for (int kt = 0; kt < 16; ++kt) {
        if (kt < 15) {   // stage W(kt+1) into o_nxt
            const char* ssrc = wfc + (size_t)(kt + 1) * FTILE;
            ldst16(ssrc + so0, lds + o_nxt + so0);
            ldst16(ssrc + so1, lds + o_nxt + so1);
            if (halfw) ldst16(ssrc + so2, lds + o_nxt + so2);
        }

        const char* bb = lds + o_cur + ncol * 1024 + lane * 16;
        const f16x8 bqh = *(const f16x8*)(bb);
        const f16x8 bql = *(const f16x8*)(bb + 8192);
        const f16x8 bkh = *(const f16x8*)(bb + 16384);
        const f16x8 bkl = *(const f16x8*)(bb + 24576);
        const f16x8 bvh = *(const f16x8*)(bb + 32768);

        accq = MFMA(ah, bqh, accq);
        accq = MFMA(al, bqh, accq);
        accq = MFMA(ah, bql, accq);
        acck = MFMA(ah, bkh, acck);
        acck = MFMA(al, bkh, acck);
        acck = MFMA(ah, bkl, acck);
        accv = MFMA(ah, bvh, accv);

        if (kt < 15) {   // A(kt+1) from the STATIC X region: pre-barrier issue
            ah = *(const f16x8*)(lds + (kt + 1) * XSTRIDE + aslot);
            al = *(const f16x8*)(lds + XLO_OFF + (kt + 1) * XSTRIDE + aslot);
        }

        asm volatile("s_waitcnt vmcnt(0)" ::: "memory");   // W(kt+1) staged
        __builtin_amdgcn_s_barrier();
        __builtin_amdgcn_sched_barrier(0);
        const int t = o_cur; o_cur = o_nxt; o_nxt = t;
    }

    // ---- softmax scratch aliases XHI[0..2304) ----
    float* part    = (float*)lds;            // [8 nstrips][64 rows]
    float* combmax = (float*)(lds + 2048);   // [64]
    float* combsum = (float*)(lds + 2304);   // [64]

    // ---- s = (q+bq)*(k+bk) into accq ----
#pragma unroll
    for (int r = 0; r < 16; ++r) {
        const int row = mt * 32 + (r & 3) + 8 * (r >> 2) + 4 * h;
        const int vv  = ncol * 32 + l31;
        const size_t bidx = ((size_t)c * Hn + h0 + row) * Wn + vv;
        const float qv = accq[r] + bq[bidx];
        const float kv = acck[r] + bk[bidx];
        accq[r] = qv * kv;
    }

    // ---- row max via DPP ror + swizzle (1 LDS op per reduce) ----
#pragma unroll
    for (int r = 0; r < 16; ++r) {
        const float m2 = rowmax32(accq[r]);
        if ((lane & 31) == r) {
            const int row = mt * 32 + (r & 3) + 8 * (r >> 2) + 4 * h;
            part[ncol * 64 + row] = m2;
        }
    }
    __syncthreads();
    if (tid < 64) {
        float m = part[tid];
#pragma unroll
        for (int w = 1; w < 8; ++w)
            m = fmaxf(m, part[w * 64 + tid]);
        combmax[tid] = m;
    }
    __syncthreads();

    // ---- e = exp(s - mx); row sum via DPP ----
#pragma unroll
    for (int r = 0; r < 16; ++r) {
        const int row = mt * 32 + (r & 3) + 8 * (r >> 2) + 4 * h;
        const float mx = combmax[row];
        const float e0 = __expf(accq[r] - mx);
        accq[r] = e0;
        const float ps = rowsum32(e0);
        if ((lane & 31) == r)
            part[ncol * 64 + row] = ps;
    }
    __syncthreads();
    if (tid < 64) {
        float s = part[tid];
#pragma unroll
        for (int w = 1; w < 8; ++w)
            s += part[w * 64 + tid];
        combsum[tid] = s;
    }
    __syncthreads();

    // ---- out = e * (v + bv) / sum ----
    float* obase = out + ((size_t)(b * Cn + c) * Hn) * Wn;
#pragma unroll
    for (int r = 0; r < 16; ++r) {
        const int row = mt * 32 + (r & 3) + 8 * (r >> 2) + 4 * h;
        const float inv = 1.0f / combsum[row];
        const int hh = h0 + row;
        const int vv = ncol * 32 + l31;
        const size_t bidx = ((size_t)c * Hn + hh) * Wn + vv;
        const float vx = accv[r] + bv[bidx];
        obase[(size_t)hh * Wn + vv] = accq[r] * vx * inv;
    }
}

// ---------------- fallback (R8): in-kernel W conversion, no ws ----------------
#define LDS_ALO 2048
#define LDS_B   4096

__global__ __launch_bounds__(512, 4) void axile_attn_mfma4(
    const float* __restrict__ x,
    const float* __restrict__ wq,
    const float* __restrict__ wk,
    const float* __restrict__ wv,
    const float* __restrict__ bq,
    const float* __restrict__ bk,
    const float* __restrict__ bv,
    float* __restrict__ out)
{
    __shared__ __align__(16) char lds[39424];

    const int tid  = threadIdx.x;
    const int ncol = tid >> 6;
    const int lane = tid & 63;
    const int h    = lane >> 5;
    const int l31  = lane & 31;

    const int blk = blockIdx.x;
    const int c   = blk & 63;
    const int j   = blk >> 6;
    const int b   = j & 7;
    const int h0  = (j >> 3) * 64;

    const float* xbase = x + ((size_t)(b * Cn + c) * Hn + h0) * Wn;
    const float* w_q = wq + (size_t)c * Wn * Wn;
    const float* w_k = wk + (size_t)c * Wn * Wn;
    const float* w_v = wv + (size_t)c * Wn * Wn;

    const int wkh = tid >> 8;
    const int n   = tid & 255;
    const int ntW = n >> 5;
    const int nl  = n & 31;
    const int wfo = ((wkh << 5) | nl) * 16;
    const int am    = tid >> 2;
    const int akq   = tid & 3;
    const int amt   = am >> 5;
    const int alc   = ((akq >> 1) << 5) | (am & 31);
    const int aboff = (akq & 1) * 8;

    f32x16 accq[2], acck[2];
#pragma unroll
    for (int mtx = 0; mtx < 2; ++mtx)
#pragma unroll
        for (int r = 0; r < 16; ++r) {
            accq[mtx][r] = 0.f;
            acck[mtx][r] = 0.f;
        }

    for (int kt = 0; kt < 16; ++kt) {
        const int k0 = kt * 16;
        __syncthreads();
#pragma unroll
        for (int mat = 0; mat < 2; ++mat) {
            const float* Wp = mat ? w_k : w_q;
            const float* wrow = Wp + (size_t)(k0 + wkh * 8) * Wn + n;
            float w8[8];
#pragma unroll
            for (int r = 0; r < 8; ++r)
                w8[r] = wrow[(size_t)r * Wn];
            f16x8 hi8, lo8;
#pragma unroll
            for (int e = 0; e < 8; ++e) {
                const float wv_ = w8[e];
                _Float16 hv = (_Float16)wv_;
                hi8[e] = hv;
                lo8[e] = (_Float16)(wv_ - (float)hv);
            }
            char* dplane = lds + LDS_B + (mat * 2) * 8192 + ntW * 1024;
            *(f16x8*)(dplane + wfo) = hi8;
            *(f16x8*)(dplane + 8192 + wfo) = lo8;
        }
        if (tid < 256) {
            const float4 xx = *(const float4*)(xbase + (size_t)am * Wn + k0 + akq * 4);
            f16x4 hi4, lo4;
            _Float16 t0 = (_Float16)xx.x; hi4[0] = t0; lo4[0] = (_Float16)(xx.x - (float)t0);
            _Float16 t1 = (_Float16)xx.y; hi4[1] = t1; lo4[1] = (_Float16)(xx.y - (float)t1);
            _Float16 t2 = (_Float16)xx.z; hi4[2] = t2; lo4[2] = (_Float16)(xx.z - (float)t2);
            _Float16 t3 = (_Float16)xx.w; hi4[3] = t3; lo4[3] = (_Float16)(xx.w - (float)t3);
            *(f16x4*)(lds + amt * 1024 + alc * 16 + aboff) = hi4;
            *(f16x4*)(lds + LDS_ALO + amt * 1024 + alc * 16 + aboff) = lo4;
        }
        __syncthreads();

        f16x8 ah[2], al[2];
#pragma unroll
        for (int mtx = 0; mtx < 2; ++mtx) {
            ah[mtx] = *(const f16x8*)(lds + mtx * 1024 + lane * 16);
            al[mtx] = *(const f16x8*)(lds + LDS_ALO + mtx * 1024 + lane * 16);
        }
        const char* bb = lds + LDS_B + ncol * 1024 + lane * 16;
        f16x8 bqh = *(const f16x8*)(bb + 0 * 8192);
        f16x8 bql = *(const f16x8*)(bb + 1 * 8192);
        f16x8 bkh = *(const f16x8*)(bb + 2 * 8192);
        f16x8 bkl = *(const f16x8*)(bb + 3 * 8192);
#pragma unroll
        for (int mtx = 0; mtx < 2; ++mtx) {
            accq[mtx] = MFMA(ah[mtx], bqh, accq[mtx]);
            accq[mtx] = MFMA(al[mtx], bqh, accq[mtx]);
            accq[mtx] = MFMA(ah[mtx], bql, accq[mtx]);
            acck[mtx] = MFMA(ah[mtx], bkh, acck[mtx]);
            acck[mtx] = MFMA(al[mtx], bkh, acck[mtx]);
            acck[mtx] = MFMA(ah[mtx], bkl, acck[mtx]);
        }
    }

    float* part    = (float*)(lds + 36864);
    float* combmax = (float*)(lds + 36864 + 2048);
    float* combsum = (float*)(lds + 36864 + 2304);

#pragma unroll
    for (int mtx = 0; mtx < 2; ++mtx)
#pragma unroll
        for (int r = 0; r < 16; ++r) {
            const int rl = (r & 3) + 8 * (r >> 2) + 4 * h;
            const int hh = h0 + mtx * 32 + rl;
            const int vv = ncol * 32 + l31;
            const size_t bidx = ((size_t)c * Hn + hh) * Wn + vv;
            const float qv = accq[mtx][r] + bq[bidx];
            const float kv = acck[mtx][r] + bk[bidx];
            accq[mtx][r] = qv * kv;
        }

#pragma unroll
    for (int mtx = 0; mtx < 2; ++mtx)
#pragma unroll
        for (int r = 0; r < 16; ++r) {
            float m2 = accq[mtx][r];
#pragma unroll
            for (int off = 16; off > 0; off >>= 1)
                m2 = fmaxf(m2, __shfl_xor(m2, off, 64));
            if ((lane & 15) == r && ((lane >> 4) & 1) == mtx) {
                const int rl  = (r & 3) + 8 * (r >> 2) + 4 * h;
                const int row = mtx * 32 + rl;
                part[ncol * 64 + row] = m2;
            }
        }
    __syncthreads();
    if (tid < 64) {
        float m = part[tid];
#pragma unroll
        for (int w = 1; w < 8; ++w)
            m = fmaxf(m, part[w * 64 + tid]);
        combmax[tid] = m;
    }
    __syncthreads();

#pragma unroll
    for (int mtx = 0; mtx < 2; ++mtx)
#pragma unroll
        for (int r = 0; r < 16; ++r) {
            const int rl  = (r & 3) + 8 * (r >> 2) + 4 * h;
            const int row = mtx * 32 + rl;
            const float mx = combmax[row];
            const float e0 = __expf(accq[mtx][r] - mx);
            accq[mtx][r] = e0;
            float ps = e0;
#pragma unroll
            for (int off = 16; off > 0; off >>= 1)
                ps += __shfl_xor(ps, off, 64);
            if ((lane & 15) == r && ((lane >> 4) & 1) == mtx)
                part[ncol * 64 + row] = ps;
        }
    __syncthreads();
    if (tid < 64) {
        float s = part[tid];
#pragma unroll
        for (int w = 1; w < 8; ++w)
            s += part[w * 64 + tid];
        combsum[tid] = s;
    }

    f32x16 accv[2];
#pragma unroll
    for (int mtx = 0; mtx < 2; ++mtx)
#pragma unroll
        for (int r = 0; r < 16; ++r)
            accv[mtx][r] = 0.f;

    for (int kt = 0; kt < 16; ++kt) {
        const int k0 = kt * 16;
        __syncthreads();
        {
            const float* wrow = w_v + (size_t)(k0 + wkh * 8) * Wn + n;
            float w8[8];
#pragma unroll
            for (int r = 0; r < 8; ++r)
                w8[r] = wrow[(size_t)r * Wn];
            f16x8 hi8;
#pragma unroll
            for (int e = 0; e < 8; ++e)
                hi8[e] = (_Float16)w8[e];
            *(f16x8*)(lds + LDS_B + ntW * 1024 + wfo) = hi8;
        }
        if (tid < 256) {
            const float4 xx = *(const float4*)(xbase + (size_t)am * Wn + k0 + akq * 4);
            f16x4 hi4;
            hi4[0] = (_Float16)xx.x;
            hi4[1] = (_Float16)xx.y;
            hi4[2] = (_Float16)xx.z;
            hi4[3] = (_Float16)xx.w;
            *(f16x4*)(lds + amt * 1024 + alc * 16 + aboff) = hi4;
        }
        __syncthreads();

        f16x8 ah[2];
#pragma unroll
        for (int mtx = 0; mtx < 2; ++mtx)
            ah[mtx] = *(const f16x8*)(lds + mtx * 1024 + lane * 16);
        f16x8 bvh = *(const f16x8*)(lds + LDS_B + ncol * 1024 + lane * 16);
#pragma unroll
        for (int mtx = 0; mtx < 2; ++mtx)
            accv[mtx] = MFMA(ah[mtx], bvh, accv[mtx]);
    }

    float* obase = out + ((size_t)(b * Cn + c) * Hn) * Wn;
#pragma unroll
    for (int mtx = 0; mtx < 2; ++mtx)
#pragma unroll
        for (int r = 0; r < 16; ++r) {
            const int rl  = (r & 3) + 8 * (r >> 2) + 4 * h;
            const int row = mtx * 32 + rl;
            const float inv = 1.0f / combsum[row];
            const int hh = h0 + row;
            const int vv = ncol * 32 + l31;
            const size_t bidx = ((size_t)c * Hn + hh) * Wn + vv;
            const float vx = accv[mtx][r] + bv[bidx];
            obase[(size_t)hh * Wn + vv] = accq[mtx][r] * vx * inv;
        }
}

extern "C" void kernel_launch(void* const* d_in, const int* in_sizes, int n_in,
                              void* d_out, int out_size, void* d_ws, size_t ws_size,
                              hipStream_t stream) {
    (void)in_sizes; (void)n_in; (void)out_size;
    const float* x  = (const float*)d_in[0];
    const float* wq = (const float*)d_in[1];
    const float* wk = (const float*)d_in[2];
    const float* wv = (const float*)d_in[3];
    const float* bq = (const float*)d_in[4];
    const float* bk = (const float*)d_in[5];
    const float* bv = (const float*)d_in[6];
    float* out = (float*)d_out;

    if (d_ws != nullptr && ws_size >= WS_NEED) {
        hipLaunchKernelGGL(prep_w, dim3(Cn * 16), dim3(256), 0, stream,
                           wq, wk, wv, (_Float16*)d_ws);
        hipLaunchKernelGGL(axile_attn_xlds2, dim3(Bn * 4 * Cn), dim3(1024), 0, stream,
                           x, (const _Float16*)d_ws, bq, bk, bv, out);
    } else {
        hipLaunchKernelGGL(axile_attn_mfma4, dim3(Bn * 4 * Cn), dim3(512), 0, stream,
                           x, wq, wk, wv, bq, bk, bv, out);
    }
}